// Round 7
// baseline (212.946 us; speedup 1.0000x reference)
//
#include <hip/hip_runtime.h>
#include <math.h>

#define BB 64
#define NN 4096
#define DD 128
#define HH 256
#define MB 256                  // rows per fused block (4 waves x 4 tiles of 16)
#define NBLK (BB * NN / MB)     // 1024 blocks, 16 per batch
#define PSTRIDE 132             // per-block partial: 128 acc + m + z (+pad)

typedef __attribute__((ext_vector_type(8))) _Float16 f16x8;
typedef __attribute__((ext_vector_type(4))) float f32x4;

// ---------------------------------------------------------------------------
// k_prep: W1 [128][256] fp32 -> Bws = W1^T as fp16 [256 cols][128 k], plain
// row-major (k contiguous). B fragments are read straight from global later.
// ---------------------------------------------------------------------------
__global__ __launch_bounds__(256) void k_prep(const float* __restrict__ W1,
                                              _Float16* __restrict__ Bws) {
    const int k = blockIdx.x;       // 0..127
    const int c = threadIdx.x;      // 0..255
    Bws[c * DD + k] = (_Float16)W1[k * HH + c];
}

// ---------------------------------------------------------------------------
// k_fused: per block of 256 rows:
//   scores (fp16 MFMA) -> local softmax (m_blk, e_i, z_blk) -> weighted
//   partial from the SAME fp16 A fragments already in registers.
// One pass over feats; B fragments stream from L2-hot global, reg dbuf.
// No barriers until the epilogue. Partials recombined exactly by k_out.
// ---------------------------------------------------------------------------
__global__ __launch_bounds__(256, 4) void k_fused(const float* __restrict__ feats,
                                                  const _Float16* __restrict__ Bws,
                                                  const float* __restrict__ b1,
                                                  const float* __restrict__ W2,
                                                  float* __restrict__ parts) {
    __shared__ float scores_l[256];
    __shared__ float ew[256];
    __shared__ float wacc[4][128];
    __shared__ float redm[4], redz[4];

    const int tid  = threadIdx.x;
    const int lane = tid & 63;
    const int wv   = tid >> 6;
    const int blk  = blockIdx.x;
    const int rl   = lane & 15;     // A row within tile / B col within chunk
    const int q    = lane >> 4;     // k-quarter (8 elems per K=32 step)

    // ---- A fragments direct from global, fp32->fp16 in regs.
    // lane (q,rl) holds rows r(t)=wv*64+t*16+rl, k = kk*32 + q*8 + e.
    f16x8 af[4][4];
    const float* fbase = feats + (size_t)blk * MB * DD;
    #pragma unroll
    for (int t = 0; t < 4; ++t) {
        const float* rp = fbase + (wv * 64 + t * 16 + rl) * DD + q * 8;
        #pragma unroll
        for (int kk = 0; kk < 4; ++kk) {
            float4 v0 = *(const float4*)(rp + kk * 32);
            float4 v1 = *(const float4*)(rp + kk * 32 + 4);
            f16x8 a;
            a[0] = (_Float16)v0.x; a[1] = (_Float16)v0.y;
            a[2] = (_Float16)v0.z; a[3] = (_Float16)v0.w;
            a[4] = (_Float16)v1.x; a[5] = (_Float16)v1.y;
            a[6] = (_Float16)v1.z; a[7] = (_Float16)v1.w;
            af[t][kk] = a;
        }
    }

    // ---- B fragment base for this lane: col = chunk*16+rl, k0 = kk*32+q*8
    const _Float16* bbase = Bws + rl * DD + q * 8;

    float sp[4][4] = {{0,0,0,0},{0,0,0,0},{0,0,0,0},{0,0,0,0}};

    f16x8 bb[2][4];
    #pragma unroll
    for (int kk = 0; kk < 4; ++kk)
        bb[0][kk] = *(const f16x8*)(bbase + kk * 32);

    #pragma unroll
    for (int chunk = 0; chunk < 16; ++chunk) {
        const int cur = chunk & 1;
        if (chunk < 15) {
            const _Float16* nb = bbase + (chunk + 1) * 16 * DD;
            #pragma unroll
            for (int kk = 0; kk < 4; ++kk)
                bb[cur ^ 1][kk] = *(const f16x8*)(nb + kk * 32);
        }
        f32x4 acc0 = {0,0,0,0}, acc1 = {0,0,0,0}, acc2 = {0,0,0,0}, acc3 = {0,0,0,0};
        #pragma unroll
        for (int kk = 0; kk < 4; ++kk) {
            const f16x8 bf = bb[cur][kk];
            acc0 = __builtin_amdgcn_mfma_f32_16x16x32_f16(af[0][kk], bf, acc0, 0, 0, 0);
            acc1 = __builtin_amdgcn_mfma_f32_16x16x32_f16(af[1][kk], bf, acc1, 0, 0, 0);
            acc2 = __builtin_amdgcn_mfma_f32_16x16x32_f16(af[2][kk], bf, acc2, 0, 0, 0);
            acc3 = __builtin_amdgcn_mfma_f32_16x16x32_f16(af[3][kk], bf, acc3, 0, 0, 0);
        }
        // fold relu + W2; D layout: col = rl, row = q*4 + j (within tile t)
        const float bbv = b1[chunk * 16 + rl];
        const float ww  = W2[chunk * 16 + rl];
        #pragma unroll
        for (int j = 0; j < 4; ++j) {
            sp[0][j] += fmaxf(acc0[j] + bbv, 0.f) * ww;
            sp[1][j] += fmaxf(acc1[j] + bbv, 0.f) * ww;
            sp[2][j] += fmaxf(acc2[j] + bbv, 0.f) * ww;
            sp[3][j] += fmaxf(acc3[j] + bbv, 0.f) * ww;
        }
    }

    // ---- scores: reduce over the 16 col-lanes (rl), publish to LDS
    #pragma unroll
    for (int m = 1; m < 16; m <<= 1)
        #pragma unroll
        for (int t = 0; t < 4; ++t)
            #pragma unroll
            for (int j = 0; j < 4; ++j)
                sp[t][j] += __shfl_xor(sp[t][j], m);
    if (rl == 0) {
        #pragma unroll
        for (int t = 0; t < 4; ++t)
            #pragma unroll
            for (int j = 0; j < 4; ++j)
                scores_l[wv * 64 + t * 16 + q * 4 + j] = sp[t][j];
    }
    __syncthreads();

    // ---- block-local softmax stats over the 256 rows
    const float s = scores_l[tid];
    float mx = s;
    #pragma unroll
    for (int o = 1; o < 64; o <<= 1) mx = fmaxf(mx, __shfl_xor(mx, o));
    if (lane == 0) redm[wv] = mx;
    __syncthreads();
    mx = fmaxf(fmaxf(redm[0], redm[1]), fmaxf(redm[2], redm[3]));
    const float e = expf(s - mx);
    ew[tid] = e;
    float z = e;
    #pragma unroll
    for (int o = 1; o < 64; o <<= 1) z += __shfl_xor(z, o);
    if (lane == 0) redz[wv] = z;
    __syncthreads();
    const float zblk = redz[0] + redz[1] + redz[2] + redz[3];

    // ---- weighted partial sum from the A fragments in registers
    const float w0 = ew[wv * 64 +  0 + rl];
    const float w1 = ew[wv * 64 + 16 + rl];
    const float w2 = ew[wv * 64 + 32 + rl];
    const float w3 = ew[wv * 64 + 48 + rl];
    float acc[4][8];
    #pragma unroll
    for (int kk = 0; kk < 4; ++kk)
        #pragma unroll
        for (int e8 = 0; e8 < 8; ++e8)
            acc[kk][e8] = w0 * (float)af[0][kk][e8] + w1 * (float)af[1][kk][e8]
                        + w2 * (float)af[2][kk][e8] + w3 * (float)af[3][kk][e8];
    // reduce over the 16 row-lanes (rl) holding the same k-slice
    #pragma unroll
    for (int m = 1; m < 16; m <<= 1)
        #pragma unroll
        for (int kk = 0; kk < 4; ++kk)
            #pragma unroll
            for (int e8 = 0; e8 < 8; ++e8)
                acc[kk][e8] += __shfl_xor(acc[kk][e8], m);
    if (rl == 0) {
        #pragma unroll
        for (int kk = 0; kk < 4; ++kk)
            #pragma unroll
            for (int e8 = 0; e8 < 8; ++e8)
                wacc[wv][kk * 32 + q * 8 + e8] = acc[kk][e8];
    }
    __syncthreads();

    // ---- fold 4 waves, emit per-block partial (128 acc + m + z)
    if (tid < 128) {
        float p = wacc[0][tid] + wacc[1][tid] + wacc[2][tid] + wacc[3][tid];
        parts[blk * PSTRIDE + tid] = p;
    } else if (tid == 128) {
        parts[blk * PSTRIDE + 128] = mx;
        parts[blk * PSTRIDE + 129] = zblk;
    }
}

// ---------------------------------------------------------------------------
// k_out: combine 16 block-partials per batch with exact softmax rescaling.
// ---------------------------------------------------------------------------
__global__ __launch_bounds__(128) void k_out(const float* __restrict__ parts,
                                             float* __restrict__ out) {
    const int b = blockIdx.x;       // 0..63
    const int d = threadIdx.x;      // 0..127
    const float* pb = parts + (size_t)b * 16 * PSTRIDE;
    float M = -1e30f;
    #pragma unroll
    for (int i = 0; i < 16; ++i) M = fmaxf(M, pb[i * PSTRIDE + 128]);
    float num = 0.f, den = 0.f;
    #pragma unroll
    for (int i = 0; i < 16; ++i) {
        const float sc = expf(pb[i * PSTRIDE + 128] - M);
        num = fmaf(sc, pb[i * PSTRIDE + d], num);
        den = fmaf(sc, pb[i * PSTRIDE + 129], den);
    }
    out[b * DD + d] = num / den;
}

extern "C" void kernel_launch(void* const* d_in, const int* in_sizes, int n_in,
                              void* d_out, int out_size, void* d_ws, size_t ws_size,
                              hipStream_t stream) {
    const float* feats = (const float*)d_in[0];
    const float* W1    = (const float*)d_in[1];
    const float* b1    = (const float*)d_in[2];
    const float* W2    = (const float*)d_in[3];
    // d_in[4] = b2: constant shift before softmax -> no effect on output.
    float* out = (float*)d_out;

    _Float16* Bws  = (_Float16*)d_ws;               // 64 KiB: W1^T fp16
    float*   parts = (float*)((char*)d_ws + 65536); // 1024 * 132 floats

    hipLaunchKernelGGL(k_prep, dim3(DD), dim3(HH), 0, stream, W1, Bws);
    hipLaunchKernelGGL(k_fused, dim3(NBLK), dim3(256), 0, stream,
                       feats, Bws, b1, W2, parts);
    hipLaunchKernelGGL(k_out, dim3(BB), dim3(128), 0, stream, parts, out);
}

// Round 8
// 132.294 us; speedup vs baseline: 1.6096x; 1.6096x over previous
//
#include <hip/hip_runtime.h>
#include <math.h>

#define BB 64
#define NN 4096
#define DD 128
#define HH 256
#define MB 128                  // rows per fused block (4 waves x 2 tiles of 16)
#define NBLK (BB * NN / MB)     // 2048 blocks, 32 per batch
#define PPB 32                  // partials per batch
#define PSTRIDE 132             // per-block partial: 128 acc + m + z (+pad)

typedef __attribute__((ext_vector_type(8))) _Float16 f16x8;
typedef __attribute__((ext_vector_type(4))) float f32x4;

// ---------------------------------------------------------------------------
// k_prep: W1 [128][256] fp32 -> Bws = W1^T as fp16 [256 cols][128 k], plain
// row-major (k contiguous). B fragments are read straight from global later.
// ---------------------------------------------------------------------------
__global__ __launch_bounds__(256) void k_prep(const float* __restrict__ W1,
                                              _Float16* __restrict__ Bws) {
    const int k = blockIdx.x;       // 0..127
    const int c = threadIdx.x;      // 0..255
    Bws[c * DD + k] = (_Float16)W1[k * HH + c];
}

// ---------------------------------------------------------------------------
// k_fused: per block of 128 rows:
//   scores (fp16 MFMA) -> local softmax (m_blk, e_i, z_blk) -> weighted
//   partial from the SAME fp16 A fragments already in registers.
// B streams from L2-hot global with a NAMED-buffer ping-pong (no runtime
// indexing -> no scratch; round-7 lesson). No barriers before the epilogue.
// ---------------------------------------------------------------------------
__global__ __launch_bounds__(256, 4) void k_fused(const float* __restrict__ feats,
                                                  const _Float16* __restrict__ Bws,
                                                  const float* __restrict__ b1,
                                                  const float* __restrict__ W2,
                                                  float* __restrict__ parts) {
    __shared__ float scores_l[128];
    __shared__ float ew[128];
    __shared__ float wacc[4][128];
    __shared__ float redm[4], redz[4];

    const int tid  = threadIdx.x;
    const int lane = tid & 63;
    const int wv   = tid >> 6;
    const int blk  = blockIdx.x;
    const int rl   = lane & 15;     // A row within tile / B col within chunk
    const int q    = lane >> 4;     // k-quarter (8 elems per K=32 step)

    // ---- A fragments direct from global, fp32->fp16 in regs.
    // lane (q,rl) holds rows r(t)=wv*32+t*16+rl, k = kk*32 + q*8 + e.
    f16x8 af[2][4];
    const float* fbase = feats + (size_t)blk * MB * DD;
    #pragma unroll
    for (int t = 0; t < 2; ++t) {
        const float* rp = fbase + (wv * 32 + t * 16 + rl) * DD + q * 8;
        #pragma unroll
        for (int kk = 0; kk < 4; ++kk) {
            float4 v0 = *(const float4*)(rp + kk * 32);
            float4 v1 = *(const float4*)(rp + kk * 32 + 4);
            f16x8 a;
            a[0] = (_Float16)v0.x; a[1] = (_Float16)v0.y;
            a[2] = (_Float16)v0.z; a[3] = (_Float16)v0.w;
            a[4] = (_Float16)v1.x; a[5] = (_Float16)v1.y;
            a[6] = (_Float16)v1.z; a[7] = (_Float16)v1.w;
            af[t][kk] = a;
        }
    }

    // ---- B fragment base for this lane: col = chunk*16+rl, k0 = kk*32+q*8
    const _Float16* bbase = Bws + rl * DD + q * 8;

    float sp[2][4] = {{0,0,0,0},{0,0,0,0}};

    f16x8 bA0, bA1, bA2, bA3, bB0, bB1, bB2, bB3;
    bA0 = *(const f16x8*)(bbase +   0);
    bA1 = *(const f16x8*)(bbase +  32);
    bA2 = *(const f16x8*)(bbase +  64);
    bA3 = *(const f16x8*)(bbase +  96);

#define COMPUTE(B0, B1, B2, B3, CH)                                              \
    do {                                                                         \
        f32x4 acc0 = {0,0,0,0}, acc1 = {0,0,0,0};                                \
        acc0 = __builtin_amdgcn_mfma_f32_16x16x32_f16(af[0][0], B0, acc0, 0,0,0);\
        acc1 = __builtin_amdgcn_mfma_f32_16x16x32_f16(af[1][0], B0, acc1, 0,0,0);\
        acc0 = __builtin_amdgcn_mfma_f32_16x16x32_f16(af[0][1], B1, acc0, 0,0,0);\
        acc1 = __builtin_amdgcn_mfma_f32_16x16x32_f16(af[1][1], B1, acc1, 0,0,0);\
        acc0 = __builtin_amdgcn_mfma_f32_16x16x32_f16(af[0][2], B2, acc0, 0,0,0);\
        acc1 = __builtin_amdgcn_mfma_f32_16x16x32_f16(af[1][2], B2, acc1, 0,0,0);\
        acc0 = __builtin_amdgcn_mfma_f32_16x16x32_f16(af[0][3], B3, acc0, 0,0,0);\
        acc1 = __builtin_amdgcn_mfma_f32_16x16x32_f16(af[1][3], B3, acc1, 0,0,0);\
        const float bbv = b1[(CH) * 16 + rl];                                    \
        const float ww  = W2[(CH) * 16 + rl];                                    \
        _Pragma("unroll")                                                        \
        for (int j = 0; j < 4; ++j) {                                            \
            sp[0][j] += fmaxf(acc0[j] + bbv, 0.f) * ww;                          \
            sp[1][j] += fmaxf(acc1[j] + bbv, 0.f) * ww;                          \
        }                                                                        \
    } while (0)

    #pragma unroll
    for (int cp = 0; cp < 8; ++cp) {
        const int c0 = cp * 2;
        // prefetch odd chunk into B while computing A
        {
            const _Float16* nb = bbase + (c0 + 1) * 16 * DD;
            bB0 = *(const f16x8*)(nb +   0);
            bB1 = *(const f16x8*)(nb +  32);
            bB2 = *(const f16x8*)(nb +  64);
            bB3 = *(const f16x8*)(nb +  96);
        }
        COMPUTE(bA0, bA1, bA2, bA3, c0);
        if (cp < 7) {
            const _Float16* nb = bbase + (c0 + 2) * 16 * DD;
            bA0 = *(const f16x8*)(nb +   0);
            bA1 = *(const f16x8*)(nb +  32);
            bA2 = *(const f16x8*)(nb +  64);
            bA3 = *(const f16x8*)(nb +  96);
        }
        COMPUTE(bB0, bB1, bB2, bB3, c0 + 1);
    }
#undef COMPUTE

    // ---- scores: reduce over the 16 col-lanes (rl), publish to LDS
    #pragma unroll
    for (int m = 1; m < 16; m <<= 1)
        #pragma unroll
        for (int t = 0; t < 2; ++t)
            #pragma unroll
            for (int j = 0; j < 4; ++j)
                sp[t][j] += __shfl_xor(sp[t][j], m);
    if (rl == 0) {
        #pragma unroll
        for (int t = 0; t < 2; ++t)
            #pragma unroll
            for (int j = 0; j < 4; ++j)
                scores_l[wv * 32 + t * 16 + q * 4 + j] = sp[t][j];
    }
    __syncthreads();

    // ---- block-local softmax stats over the 128 rows (each value held by
    // two threads: tid and tid+128 -> sums count everything exactly twice)
    const float s = scores_l[tid & 127];
    float mx = s;
    #pragma unroll
    for (int o = 1; o < 64; o <<= 1) mx = fmaxf(mx, __shfl_xor(mx, o));
    if (lane == 0) redm[wv] = mx;
    __syncthreads();
    mx = fmaxf(fmaxf(redm[0], redm[1]), fmaxf(redm[2], redm[3]));
    const float e = expf(s - mx);
    if (tid < 128) ew[tid] = e;
    float z = e;
    #pragma unroll
    for (int o = 1; o < 64; o <<= 1) z += __shfl_xor(z, o);
    if (lane == 0) redz[wv] = z;
    __syncthreads();
    const float zblk = 0.5f * (redz[0] + redz[1] + redz[2] + redz[3]);

    // ---- weighted partial sum from the A fragments in registers
    const float w0 = ew[wv * 32 +  0 + rl];
    const float w1 = ew[wv * 32 + 16 + rl];
    float acc[4][8];
    #pragma unroll
    for (int kk = 0; kk < 4; ++kk)
        #pragma unroll
        for (int e8 = 0; e8 < 8; ++e8)
            acc[kk][e8] = w0 * (float)af[0][kk][e8] + w1 * (float)af[1][kk][e8];
    // reduce over the 16 row-lanes (rl) holding the same k-slice
    #pragma unroll
    for (int m = 1; m < 16; m <<= 1)
        #pragma unroll
        for (int kk = 0; kk < 4; ++kk)
            #pragma unroll
            for (int e8 = 0; e8 < 8; ++e8)
                acc[kk][e8] += __shfl_xor(acc[kk][e8], m);
    if (rl == 0) {
        #pragma unroll
        for (int kk = 0; kk < 4; ++kk)
            #pragma unroll
            for (int e8 = 0; e8 < 8; ++e8)
                wacc[wv][kk * 32 + q * 8 + e8] = acc[kk][e8];
    }
    __syncthreads();

    // ---- fold 4 waves, emit per-block partial (128 acc + m + z)
    if (tid < 128) {
        float p = wacc[0][tid] + wacc[1][tid] + wacc[2][tid] + wacc[3][tid];
        parts[blk * PSTRIDE + tid] = p;
    } else if (tid == 128) {
        parts[blk * PSTRIDE + 128] = mx;
        parts[blk * PSTRIDE + 129] = zblk;
    }
}

// ---------------------------------------------------------------------------
// k_out: combine 32 block-partials per batch with exact softmax rescaling.
// ---------------------------------------------------------------------------
__global__ __launch_bounds__(128) void k_out(const float* __restrict__ parts,
                                             float* __restrict__ out) {
    const int b = blockIdx.x;       // 0..63
    const int d = threadIdx.x;      // 0..127
    const float* pb = parts + (size_t)b * PPB * PSTRIDE;
    float M = -1e30f;
    #pragma unroll
    for (int i = 0; i < PPB; ++i) M = fmaxf(M, pb[i * PSTRIDE + 128]);
    float num = 0.f, den = 0.f;
    #pragma unroll
    for (int i = 0; i < PPB; ++i) {
        const float sc = expf(pb[i * PSTRIDE + 128] - M);
        num = fmaf(sc, pb[i * PSTRIDE + d], num);
        den = fmaf(sc, pb[i * PSTRIDE + 129], den);
    }
    out[b * DD + d] = num / den;
}

extern "C" void kernel_launch(void* const* d_in, const int* in_sizes, int n_in,
                              void* d_out, int out_size, void* d_ws, size_t ws_size,
                              hipStream_t stream) {
    const float* feats = (const float*)d_in[0];
    const float* W1    = (const float*)d_in[1];
    const float* b1    = (const float*)d_in[2];
    const float* W2    = (const float*)d_in[3];
    // d_in[4] = b2: constant shift before softmax -> no effect on output.
    float* out = (float*)d_out;

    _Float16* Bws  = (_Float16*)d_ws;               // 64 KiB: W1^T fp16
    float*   parts = (float*)((char*)d_ws + 65536); // 2048 * 132 floats

    hipLaunchKernelGGL(k_prep, dim3(DD), dim3(HH), 0, stream, W1, Bws);
    hipLaunchKernelGGL(k_fused, dim3(NBLK), dim3(256), 0, stream,
                       feats, Bws, b1, W2, parts);
    hipLaunchKernelGGL(k_out, dim3(BB), dim3(128), 0, stream, parts, out);
}

// Round 9
// 111.018 us; speedup vs baseline: 1.9181x; 1.1916x over previous
//
#include <hip/hip_runtime.h>
#include <math.h>

#define BB 64
#define NN 4096
#define DD 128
#define HH 256
#define MB 128                  // rows per fused block (4 waves x 2 tiles of 16)
#define NBLK (BB * NN / MB)     // 2048 blocks, 32 per batch
#define PPB 32                  // partials per batch
#define PSTRIDE 132             // per-block partial: 128 acc + m + z (+pad)

typedef __attribute__((ext_vector_type(8))) _Float16 f16x8;
typedef __attribute__((ext_vector_type(4))) float f32x4;

// ---------------------------------------------------------------------------
// k_prep: W1 [128][256] fp32 -> Bws = W1^T as fp16 [256 cols][128 k], plain
// row-major (k contiguous). B fragments are read straight from global later.
// ---------------------------------------------------------------------------
__global__ __launch_bounds__(256) void k_prep(const float* __restrict__ W1,
                                              _Float16* __restrict__ Bws) {
    const int k = blockIdx.x;       // 0..127
    const int c = threadIdx.x;      // 0..255
    Bws[c * DD + k] = (_Float16)W1[k * HH + c];
}

// ---------------------------------------------------------------------------
// k_fused: per block of 128 rows:
//   scores (fp16 MFMA) -> local softmax (m_blk, e_i, z_blk) -> weighted
//   partial from the SAME fp16 A fragments already in registers.
// B streams from L2-hot global with a NAMED-buffer ping-pong (rule #20).
// NOTE round-8 lesson: __launch_bounds__(256,4) made the allocator target
// 8 waves/EU -> 64-VGPR budget -> 160 MB of scratch spill. (256,2) gives a
// ~92-110 VGPR allocation (no spill) which still lands in the 4-waves/EU
// occupancy granule. Do NOT raise the second arg.
// ---------------------------------------------------------------------------
__global__ __launch_bounds__(256, 2) void k_fused(const float* __restrict__ feats,
                                                  const _Float16* __restrict__ Bws,
                                                  const float* __restrict__ b1,
                                                  const float* __restrict__ W2,
                                                  float* __restrict__ parts) {
    __shared__ float scores_l[128];
    __shared__ float ew[128];
    __shared__ float wacc[4][128];
    __shared__ float redm[4], redz[4];

    const int tid  = threadIdx.x;
    const int lane = tid & 63;
    const int wv   = tid >> 6;
    const int blk  = blockIdx.x;
    const int rl   = lane & 15;     // A row within tile / B col within chunk
    const int q    = lane >> 4;     // k-quarter (8 elems per K=32 step)

    // ---- A fragments direct from global, fp32->fp16 in regs.
    // lane (q,rl) holds rows r(t)=wv*32+t*16+rl, k = kk*32 + q*8 + e.
    f16x8 af[2][4];
    const float* fbase = feats + (size_t)blk * MB * DD;
    #pragma unroll
    for (int t = 0; t < 2; ++t) {
        const float* rp = fbase + (wv * 32 + t * 16 + rl) * DD + q * 8;
        #pragma unroll
        for (int kk = 0; kk < 4; ++kk) {
            float4 v0 = *(const float4*)(rp + kk * 32);
            float4 v1 = *(const float4*)(rp + kk * 32 + 4);
            f16x8 a;
            a[0] = (_Float16)v0.x; a[1] = (_Float16)v0.y;
            a[2] = (_Float16)v0.z; a[3] = (_Float16)v0.w;
            a[4] = (_Float16)v1.x; a[5] = (_Float16)v1.y;
            a[6] = (_Float16)v1.z; a[7] = (_Float16)v1.w;
            af[t][kk] = a;
        }
    }

    // ---- B fragment base for this lane: col = chunk*16+rl, k0 = kk*32+q*8
    const _Float16* bbase = Bws + rl * DD + q * 8;

    float sp[2][4] = {{0,0,0,0},{0,0,0,0}};

    f16x8 bA0, bA1, bA2, bA3, bB0, bB1, bB2, bB3;
    bA0 = *(const f16x8*)(bbase +   0);
    bA1 = *(const f16x8*)(bbase +  32);
    bA2 = *(const f16x8*)(bbase +  64);
    bA3 = *(const f16x8*)(bbase +  96);

#define COMPUTE(B0, B1, B2, B3, CH)                                              \
    do {                                                                         \
        f32x4 acc0 = {0,0,0,0}, acc1 = {0,0,0,0};                                \
        acc0 = __builtin_amdgcn_mfma_f32_16x16x32_f16(af[0][0], B0, acc0, 0,0,0);\
        acc1 = __builtin_amdgcn_mfma_f32_16x16x32_f16(af[1][0], B0, acc1, 0,0,0);\
        acc0 = __builtin_amdgcn_mfma_f32_16x16x32_f16(af[0][1], B1, acc0, 0,0,0);\
        acc1 = __builtin_amdgcn_mfma_f32_16x16x32_f16(af[1][1], B1, acc1, 0,0,0);\
        acc0 = __builtin_amdgcn_mfma_f32_16x16x32_f16(af[0][2], B2, acc0, 0,0,0);\
        acc1 = __builtin_amdgcn_mfma_f32_16x16x32_f16(af[1][2], B2, acc1, 0,0,0);\
        acc0 = __builtin_amdgcn_mfma_f32_16x16x32_f16(af[0][3], B3, acc0, 0,0,0);\
        acc1 = __builtin_amdgcn_mfma_f32_16x16x32_f16(af[1][3], B3, acc1, 0,0,0);\
        const float bbv = b1[(CH) * 16 + rl];                                    \
        const float ww  = W2[(CH) * 16 + rl];                                    \
        _Pragma("unroll")                                                        \
        for (int j = 0; j < 4; ++j) {                                            \
            sp[0][j] += fmaxf(acc0[j] + bbv, 0.f) * ww;                          \
            sp[1][j] += fmaxf(acc1[j] + bbv, 0.f) * ww;                          \
        }                                                                        \
    } while (0)

    #pragma unroll
    for (int cp = 0; cp < 8; ++cp) {
        const int c0 = cp * 2;
        // prefetch odd chunk into B while computing A
        {
            const _Float16* nb = bbase + (c0 + 1) * 16 * DD;
            bB0 = *(const f16x8*)(nb +   0);
            bB1 = *(const f16x8*)(nb +  32);
            bB2 = *(const f16x8*)(nb +  64);
            bB3 = *(const f16x8*)(nb +  96);
        }
        COMPUTE(bA0, bA1, bA2, bA3, c0);
        if (cp < 7) {
            const _Float16* nb = bbase + (c0 + 2) * 16 * DD;
            bA0 = *(const f16x8*)(nb +   0);
            bA1 = *(const f16x8*)(nb +  32);
            bA2 = *(const f16x8*)(nb +  64);
            bA3 = *(const f16x8*)(nb +  96);
        }
        COMPUTE(bB0, bB1, bB2, bB3, c0 + 1);
    }
#undef COMPUTE

    // ---- scores: reduce over the 16 col-lanes (rl), publish to LDS
    #pragma unroll
    for (int m = 1; m < 16; m <<= 1)
        #pragma unroll
        for (int t = 0; t < 2; ++t)
            #pragma unroll
            for (int j = 0; j < 4; ++j)
                sp[t][j] += __shfl_xor(sp[t][j], m);
    if (rl == 0) {
        #pragma unroll
        for (int t = 0; t < 2; ++t)
            #pragma unroll
            for (int j = 0; j < 4; ++j)
                scores_l[wv * 32 + t * 16 + q * 4 + j] = sp[t][j];
    }
    __syncthreads();

    // ---- block-local softmax stats over the 128 rows (each value held by
    // two threads: tid and tid+128 -> sums count everything exactly twice)
    const float s = scores_l[tid & 127];
    float mx = s;
    #pragma unroll
    for (int o = 1; o < 64; o <<= 1) mx = fmaxf(mx, __shfl_xor(mx, o));
    if (lane == 0) redm[wv] = mx;
    __syncthreads();
    mx = fmaxf(fmaxf(redm[0], redm[1]), fmaxf(redm[2], redm[3]));
    const float e = expf(s - mx);
    if (tid < 128) ew[tid] = e;
    float z = e;
    #pragma unroll
    for (int o = 1; o < 64; o <<= 1) z += __shfl_xor(z, o);
    if (lane == 0) redz[wv] = z;
    __syncthreads();
    const float zblk = 0.5f * (redz[0] + redz[1] + redz[2] + redz[3]);

    // ---- weighted partial sum from the A fragments in registers
    const float w0 = ew[wv * 32 +  0 + rl];
    const float w1 = ew[wv * 32 + 16 + rl];
    float acc[4][8];
    #pragma unroll
    for (int kk = 0; kk < 4; ++kk)
        #pragma unroll
        for (int e8 = 0; e8 < 8; ++e8)
            acc[kk][e8] = w0 * (float)af[0][kk][e8] + w1 * (float)af[1][kk][e8];
    // reduce over the 16 row-lanes (rl) holding the same k-slice
    #pragma unroll
    for (int m = 1; m < 16; m <<= 1)
        #pragma unroll
        for (int kk = 0; kk < 4; ++kk)
            #pragma unroll
            for (int e8 = 0; e8 < 8; ++e8)
                acc[kk][e8] += __shfl_xor(acc[kk][e8], m);
    if (rl == 0) {
        #pragma unroll
        for (int kk = 0; kk < 4; ++kk)
            #pragma unroll
            for (int e8 = 0; e8 < 8; ++e8)
                wacc[wv][kk * 32 + q * 8 + e8] = acc[kk][e8];
    }
    __syncthreads();

    // ---- fold 4 waves, emit per-block partial (128 acc + m + z)
    if (tid < 128) {
        float p = wacc[0][tid] + wacc[1][tid] + wacc[2][tid] + wacc[3][tid];
        parts[blk * PSTRIDE + tid] = p;
    } else if (tid == 128) {
        parts[blk * PSTRIDE + 128] = mx;
        parts[blk * PSTRIDE + 129] = zblk;
    }
}

// ---------------------------------------------------------------------------
// k_out: combine 32 block-partials per batch with exact softmax rescaling.
// ---------------------------------------------------------------------------
__global__ __launch_bounds__(128) void k_out(const float* __restrict__ parts,
                                             float* __restrict__ out) {
    const int b = blockIdx.x;       // 0..63
    const int d = threadIdx.x;      // 0..127
    const float* pb = parts + (size_t)b * PPB * PSTRIDE;
    float M = -1e30f;
    #pragma unroll
    for (int i = 0; i < PPB; ++i) M = fmaxf(M, pb[i * PSTRIDE + 128]);
    float num = 0.f, den = 0.f;
    #pragma unroll
    for (int i = 0; i < PPB; ++i) {
        const float sc = expf(pb[i * PSTRIDE + 128] - M);
        num = fmaf(sc, pb[i * PSTRIDE + d], num);
        den = fmaf(sc, pb[i * PSTRIDE + 129], den);
    }
    out[b * DD + d] = num / den;
}

extern "C" void kernel_launch(void* const* d_in, const int* in_sizes, int n_in,
                              void* d_out, int out_size, void* d_ws, size_t ws_size,
                              hipStream_t stream) {
    const float* feats = (const float*)d_in[0];
    const float* W1    = (const float*)d_in[1];
    const float* b1    = (const float*)d_in[2];
    const float* W2    = (const float*)d_in[3];
    // d_in[4] = b2: constant shift before softmax -> no effect on output.
    float* out = (float*)d_out;

    _Float16* Bws  = (_Float16*)d_ws;               // 64 KiB: W1^T fp16
    float*   parts = (float*)((char*)d_ws + 65536); // 2048 * 132 floats

    hipLaunchKernelGGL(k_prep, dim3(DD), dim3(HH), 0, stream, W1, Bws);
    hipLaunchKernelGGL(k_fused, dim3(NBLK), dim3(256), 0, stream,
                       feats, Bws, b1, W2, parts);
    hipLaunchKernelGGL(k_out, dim3(BB), dim3(128), 0, stream, parts, out);
}

// Round 10
// 68.577 us; speedup vs baseline: 3.1052x; 1.6189x over previous
//
#include <hip/hip_runtime.h>
#include <math.h>

#define BB 64
#define NN 4096
#define DD 128
#define HH 256
#define MB 256                  // rows per fused block (4 waves x 4 tiles of 16)
#define NBLK (BB * NN / MB)     // 1024 blocks, 16 per batch
#define PPB 16                  // partials per batch
#define PSTRIDE 132             // per-block partial: 128 acc + m + z (+pad)

typedef __attribute__((ext_vector_type(8))) _Float16 f16x8;
typedef __attribute__((ext_vector_type(4))) float f32x4;

static __device__ __forceinline__ void gload_lds16(const void* g, void* l) {
    __builtin_amdgcn_global_load_lds(
        (const __attribute__((address_space(1))) unsigned int*)g,
        (__attribute__((address_space(3))) unsigned int*)l, 16, 0, 0);
}

// ---------------------------------------------------------------------------
// k_prep: W1 [128][256] fp32 -> Bws fp16, transposed per 16-col chunk,
// XOR-swizzled exactly as it will sit in LDS (linear global_load_lds copy).
// chunk region = 4096 B; elem (cl, k) at ((cl<<8)+(k<<1)) ^ ((cl&7)<<4).
// ---------------------------------------------------------------------------
__global__ __launch_bounds__(256) void k_prep(const float* __restrict__ W1,
                                              char* __restrict__ Bws) {
    const int k = blockIdx.x;       // 0..127
    const int c = threadIdx.x;      // 0..255
    const _Float16 h = (_Float16)W1[k * HH + c];
    const int chunk = c >> 4, cl = c & 15;
    const int off = ((cl << 8) + (k << 1)) ^ ((cl & 7) << 4);
    *(_Float16*)(Bws + chunk * 4096 + off) = h;
}

// ---------------------------------------------------------------------------
// k_fused (round-6 structure, B staged in TWO 32 KiB phases):
//   scores (fp16 MFMA) -> block-local softmax -> weighted partial from the
//   SAME fp16 A fragments in registers. One pass over feats.
// LDS ~37 KiB -> 4 blocks/CU (r6's 70 KiB capped at 2). VGPR ~92 (r8 lesson:
// keep launch_bounds min-waves at 2; raising it forces spill).
// ---------------------------------------------------------------------------
__global__ __launch_bounds__(256, 2) void k_fused(const float* __restrict__ feats,
                                                  const char* __restrict__ Bws,
                                                  const float* __restrict__ b1,
                                                  const float* __restrict__ W2,
                                                  float* __restrict__ parts) {
    __shared__ char  Bl[32768];     // 8 chunks x 16 cols x 128 k, fp16 swizzled
    __shared__ float scores_l[256];
    __shared__ float ew[256];
    __shared__ float wacc[4][128];
    __shared__ float redm[4], redz[4];

    const int tid  = threadIdx.x;
    const int lane = tid & 63;
    const int wv   = tid >> 6;
    const int blk  = blockIdx.x;
    const int rl   = lane & 15;     // A row within tile / B col within chunk
    const int q    = lane >> 4;     // k-quarter (8 elems per K=32 step)

    // ---- stage B phase 0 (chunks 0..7): 32 KiB = 8 iters x 256 x 16 B
    #pragma unroll
    for (int it = 0; it < 8; ++it)
        gload_lds16(Bws + it * 4096 + tid * 16, Bl + it * 4096 + tid * 16);

    // ---- A fragments direct from global, fp32->fp16 in regs.
    // lane (q,rl) holds rows r(t)=wv*64+t*16+rl, k = kk*32 + q*8 + e.
    f16x8 af[4][4];
    const float* fbase = feats + (size_t)blk * MB * DD;
    #pragma unroll
    for (int t = 0; t < 4; ++t) {
        const float* rp = fbase + (wv * 64 + t * 16 + rl) * DD + q * 8;
        #pragma unroll
        for (int kk = 0; kk < 4; ++kk) {
            float4 v0 = *(const float4*)(rp + kk * 32);
            float4 v1 = *(const float4*)(rp + kk * 32 + 4);
            f16x8 a;
            a[0] = (_Float16)v0.x; a[1] = (_Float16)v0.y;
            a[2] = (_Float16)v0.z; a[3] = (_Float16)v0.w;
            a[4] = (_Float16)v1.x; a[5] = (_Float16)v1.y;
            a[6] = (_Float16)v1.z; a[7] = (_Float16)v1.w;
            af[t][kk] = a;
        }
    }
    __syncthreads();                // phase-0 B staged (vmcnt drained)

    float sp[4][4] = {{0,0,0,0},{0,0,0,0},{0,0,0,0},{0,0,0,0}};
    const int brow = rl << 8;
    const int bswz = (rl & 7) << 4;
    const int bq   = q << 4;

#define CHUNK_COMPUTE(CHUNK)                                                       \
    do {                                                                           \
        const float bbv = b1[(CHUNK) * 16 + rl];                                   \
        const float ww  = W2[(CHUNK) * 16 + rl];                                   \
        const char* cb = Bl + ((CHUNK) & 7) * 4096;                                \
        f32x4 acc0 = {0,0,0,0}, acc1 = {0,0,0,0}, acc2 = {0,0,0,0}, acc3 = {0,0,0,0};\
        _Pragma("unroll")                                                          \
        for (int kk = 0; kk < 4; ++kk) {                                           \
            f16x8 bf = *(const f16x8*)(cb + (((brow + (kk << 6) + bq)) ^ bswz));   \
            acc0 = __builtin_amdgcn_mfma_f32_16x16x32_f16(af[0][kk], bf, acc0, 0,0,0);\
            acc1 = __builtin_amdgcn_mfma_f32_16x16x32_f16(af[1][kk], bf, acc1, 0,0,0);\
            acc2 = __builtin_amdgcn_mfma_f32_16x16x32_f16(af[2][kk], bf, acc2, 0,0,0);\
            acc3 = __builtin_amdgcn_mfma_f32_16x16x32_f16(af[3][kk], bf, acc3, 0,0,0);\
        }                                                                          \
        _Pragma("unroll")                                                          \
        for (int j = 0; j < 4; ++j) {                                              \
            sp[0][j] += fmaxf(acc0[j] + bbv, 0.f) * ww;                            \
            sp[1][j] += fmaxf(acc1[j] + bbv, 0.f) * ww;                            \
            sp[2][j] += fmaxf(acc2[j] + bbv, 0.f) * ww;                            \
            sp[3][j] += fmaxf(acc3[j] + bbv, 0.f) * ww;                            \
        }                                                                          \
    } while (0)

    #pragma unroll
    for (int chunk = 0; chunk < 8; ++chunk) CHUNK_COMPUTE(chunk);

    __syncthreads();                // all waves done reading phase-0 B
    // ---- stage B phase 1 (chunks 8..15) into the same buffer
    #pragma unroll
    for (int it = 0; it < 8; ++it)
        gload_lds16(Bws + 32768 + it * 4096 + tid * 16, Bl + it * 4096 + tid * 16);
    __syncthreads();                // phase-1 B staged

    #pragma unroll
    for (int chunk = 8; chunk < 16; ++chunk) CHUNK_COMPUTE(chunk);
#undef CHUNK_COMPUTE

    // ---- scores: reduce over the 16 col-lanes (rl), publish to LDS
    #pragma unroll
    for (int m = 1; m < 16; m <<= 1)
        #pragma unroll
        for (int t = 0; t < 4; ++t)
            #pragma unroll
            for (int j = 0; j < 4; ++j)
                sp[t][j] += __shfl_xor(sp[t][j], m);
    if (rl == 0) {
        #pragma unroll
        for (int t = 0; t < 4; ++t)
            #pragma unroll
            for (int j = 0; j < 4; ++j)
                scores_l[wv * 64 + t * 16 + q * 4 + j] = sp[t][j];
    }
    __syncthreads();

    // ---- block-local softmax stats over the 256 rows
    const float s = scores_l[tid];
    float mx = s;
    #pragma unroll
    for (int o = 1; o < 64; o <<= 1) mx = fmaxf(mx, __shfl_xor(mx, o));
    if (lane == 0) redm[wv] = mx;
    __syncthreads();
    mx = fmaxf(fmaxf(redm[0], redm[1]), fmaxf(redm[2], redm[3]));
    const float e = expf(s - mx);
    ew[tid] = e;
    float z = e;
    #pragma unroll
    for (int o = 1; o < 64; o <<= 1) z += __shfl_xor(z, o);
    if (lane == 0) redz[wv] = z;
    __syncthreads();
    const float zblk = redz[0] + redz[1] + redz[2] + redz[3];

    // ---- weighted partial sum from the A fragments in registers
    const float w0 = ew[wv * 64 +  0 + rl];
    const float w1 = ew[wv * 64 + 16 + rl];
    const float w2 = ew[wv * 64 + 32 + rl];
    const float w3 = ew[wv * 64 + 48 + rl];
    float acc[4][8];
    #pragma unroll
    for (int kk = 0; kk < 4; ++kk)
        #pragma unroll
        for (int e8 = 0; e8 < 8; ++e8)
            acc[kk][e8] = w0 * (float)af[0][kk][e8] + w1 * (float)af[1][kk][e8]
                        + w2 * (float)af[2][kk][e8] + w3 * (float)af[3][kk][e8];
    // reduce over the 16 row-lanes (rl) holding the same k-slice
    #pragma unroll
    for (int m = 1; m < 16; m <<= 1)
        #pragma unroll
        for (int kk = 0; kk < 4; ++kk)
            #pragma unroll
            for (int e8 = 0; e8 < 8; ++e8)
                acc[kk][e8] += __shfl_xor(acc[kk][e8], m);
    if (rl == 0) {
        #pragma unroll
        for (int kk = 0; kk < 4; ++kk)
            #pragma unroll
            for (int e8 = 0; e8 < 8; ++e8)
                wacc[wv][kk * 32 + q * 8 + e8] = acc[kk][e8];
    }
    __syncthreads();

    // ---- fold 4 waves, emit per-block partial (128 acc + m + z)
    if (tid < 128) {
        float p = wacc[0][tid] + wacc[1][tid] + wacc[2][tid] + wacc[3][tid];
        parts[blk * PSTRIDE + tid] = p;
    } else if (tid == 128) {
        parts[blk * PSTRIDE + 128] = mx;
        parts[blk * PSTRIDE + 129] = zblk;
    }
}

// ---------------------------------------------------------------------------
// k_out: combine 16 block-partials per batch with exact softmax rescaling.
// ---------------------------------------------------------------------------
__global__ __launch_bounds__(128) void k_out(const float* __restrict__ parts,
                                             float* __restrict__ out) {
    const int b = blockIdx.x;       // 0..63
    const int d = threadIdx.x;      // 0..127
    const float* pb = parts + (size_t)b * PPB * PSTRIDE;
    float M = -1e30f;
    #pragma unroll
    for (int i = 0; i < PPB; ++i) M = fmaxf(M, pb[i * PSTRIDE + 128]);
    float num = 0.f, den = 0.f;
    #pragma unroll
    for (int i = 0; i < PPB; ++i) {
        const float sc = expf(pb[i * PSTRIDE + 128] - M);
        num = fmaf(sc, pb[i * PSTRIDE + d], num);
        den = fmaf(sc, pb[i * PSTRIDE + 129], den);
    }
    out[b * DD + d] = num / den;
}

extern "C" void kernel_launch(void* const* d_in, const int* in_sizes, int n_in,
                              void* d_out, int out_size, void* d_ws, size_t ws_size,
                              hipStream_t stream) {
    const float* feats = (const float*)d_in[0];
    const float* W1    = (const float*)d_in[1];
    const float* b1    = (const float*)d_in[2];
    const float* W2    = (const float*)d_in[3];
    // d_in[4] = b2: constant shift before softmax -> no effect on output.
    float* out = (float*)d_out;

    char*  Bws   = (char*)d_ws;                     // 64 KiB: W1t fp16 swizzled
    float* parts = (float*)((char*)d_ws + 65536);   // 1024 * 132 floats

    hipLaunchKernelGGL(k_prep, dim3(DD), dim3(HH), 0, stream, W1, Bws);
    hipLaunchKernelGGL(k_fused, dim3(NBLK), dim3(256), 0, stream,
                       feats, Bws, b1, W2, parts);
    hipLaunchKernelGGL(k_out, dim3(BB), dim3(128), 0, stream, parts, out);
}